// Round 1
// baseline (6752.551 us; speedup 1.0000x reference)
//
#include <hip/hip_runtime.h>
#include <cstdint>
#include <cmath>

#define D_DIM   2048
#define S_DIM   1024
#define B_DIM   2
#define H_DIM   16
#define HD_DIM  128
#define MLP_DIM 8192
#define T_DIM   (B_DIM * S_DIM)   // 2048 tokens

// ---------------- block reductions (256 threads) ----------------
__device__ inline float block_reduce_sum_256(float v, float* sm) {
    int tid = threadIdx.x;
    sm[tid] = v; __syncthreads();
    for (int s = 128; s > 0; s >>= 1) {
        if (tid < s) sm[tid] += sm[tid + s];
        __syncthreads();
    }
    float r = sm[0]; __syncthreads();
    return r;
}
__device__ inline float block_reduce_max_256(float v, float* sm) {
    int tid = threadIdx.x;
    sm[tid] = v; __syncthreads();
    for (int s = 128; s > 0; s >>= 1) {
        if (tid < s) sm[tid] = fmaxf(sm[tid], sm[tid + s]);
        __syncthreads();
    }
    float r = sm[0]; __syncthreads();
    return r;
}

// ---------------- weight scale: sum |w| (two-stage, deterministic) ----------------
__global__ void wabs_partial(const float* __restrict__ w, int n, float* __restrict__ part) {
    __shared__ float sm[256];
    float s = 0.f;
    for (int i = blockIdx.x * 256 + threadIdx.x; i < n; i += 256 * gridDim.x)
        s += fabsf(w[i]);
    float tot = block_reduce_sum_256(s, sm);
    if (threadIdx.x == 0) part[blockIdx.x] = tot;
}
__global__ void wabs_final(const float* __restrict__ part, int np, float count, float* __restrict__ out) {
    __shared__ float sm[256];
    float s = 0.f;
    for (int i = threadIdx.x; i < np; i += 256) s += part[i];
    float tot = block_reduce_sum_256(s, sm);
    if (threadIdx.x == 0) out[0] = tot / count + 1e-8f;
}

// ---------------- ternary weight quantization ----------------
__global__ void quant_w(const float* __restrict__ w, int n, const float* __restrict__ wsp,
                        int8_t* __restrict__ q) {
    float ws = wsp[0];
    for (int i = blockIdx.x * 256 + threadIdx.x; i < n; i += 256 * gridDim.x) {
        float v = rintf(w[i] / ws);            // jnp.round = half-to-even = rintf
        v = fminf(1.f, fmaxf(-1.f, v));
        q[i] = (int8_t)v;
    }
}

// ---------------- fused rmsnorm + activation quantization (one block per token) ----------------
__global__ void rmsnorm_quant(const float* __restrict__ x, const float* __restrict__ nw,
                              int8_t* __restrict__ q, float* __restrict__ ascale, int Kdim) {
    __shared__ float sm[256];
    int t = blockIdx.x;
    const float* row = x + (size_t)t * Kdim;
    float s = 0.f;
    for (int i = threadIdx.x; i < Kdim; i += 256) { float v = row[i]; s += v * v; }
    float tot = block_reduce_sum_256(s, sm);
    float rms = sqrtf(tot / (float)Kdim + 1e-6f);
    float m = 0.f;
    for (int i = threadIdx.x; i < Kdim; i += 256) {
        float h = row[i] / rms * nw[i];
        m = fmaxf(m, fabsf(h));
    }
    float amax = block_reduce_max_256(m, sm);
    float as = amax + 1e-8f;
    if (threadIdx.x == 0) ascale[t] = as;
    for (int i = threadIdx.x; i < Kdim; i += 256) {
        float h = row[i] / rms * nw[i];
        float v = rintf(fminf(127.f, fmaxf(-128.f, h / as * 127.f)));
        q[(size_t)t * Kdim + i] = (int8_t)v;
    }
}

// ---------------- activation quantization, no norm (one block per token) ----------------
__global__ void act_quant(const float* __restrict__ x, int8_t* __restrict__ q,
                          float* __restrict__ ascale, int Kdim) {
    __shared__ float sm[256];
    int t = blockIdx.x;
    const float* row = x + (size_t)t * Kdim;
    float m = 0.f;
    for (int i = threadIdx.x; i < Kdim; i += 256) m = fmaxf(m, fabsf(row[i]));
    float amax = block_reduce_max_256(m, sm);
    float as = amax + 1e-8f;
    if (threadIdx.x == 0) ascale[t] = as;
    for (int i = threadIdx.x; i < Kdim; i += 256) {
        float v = rintf(fminf(127.f, fmaxf(-128.f, row[i] / as * 127.f)));
        q[(size_t)t * Kdim + i] = (int8_t)v;
    }
}

// ---------------- int8-in / fp32-exact GEMM:  out[t,n] = (sum_k A[t,k]*W[n,k]) * ws*as[t]/127 ----------------
// mode 0: plain store   mode 1: += aux[t,n] (residual)   mode 2: silu(v) * aux[t,n]
// 64x64 block tile, 256 threads, 4x4 per thread, BK=32, transposed LDS tiles (float4 reads).
__global__ __launch_bounds__(256) void gemm_q8(
        const int8_t* __restrict__ Aq, const int8_t* __restrict__ Wq,
        float* __restrict__ out, const float* __restrict__ ascale,
        const float* __restrict__ wscale_p, const float* __restrict__ aux,
        int T, int N, int K, int mode) {
    __shared__ float As[32][68];   // [kk][row], pad 68 to avoid bank conflicts
    __shared__ float Bs[32][68];
    const int tid = threadIdx.x;
    const int tx = tid & 15, ty = tid >> 4;
    const int m0 = blockIdx.y * 64, n0 = blockIdx.x * 64;
    const int Kw = K >> 2;
    const int* A4 = (const int*)Aq;
    const int* B4 = (const int*)Wq;
    float acc[4][4] = {};
    for (int k0 = 0; k0 < Kw; k0 += 8) {
        #pragma unroll
        for (int p = 0; p < 2; p++) {
            int idx = tid + p * 256;
            int r = idx >> 3, j = idx & 7;
            int va = A4[(size_t)(m0 + r) * Kw + k0 + j];
            int vb = B4[(size_t)(n0 + r) * Kw + k0 + j];
            As[j * 4 + 0][r] = (float)((va << 24) >> 24);
            As[j * 4 + 1][r] = (float)((va << 16) >> 24);
            As[j * 4 + 2][r] = (float)((va << 8) >> 24);
            As[j * 4 + 3][r] = (float)(va >> 24);
            Bs[j * 4 + 0][r] = (float)((vb << 24) >> 24);
            Bs[j * 4 + 1][r] = (float)((vb << 16) >> 24);
            Bs[j * 4 + 2][r] = (float)((vb << 8) >> 24);
            Bs[j * 4 + 3][r] = (float)(vb >> 24);
        }
        __syncthreads();
        #pragma unroll
        for (int kk = 0; kk < 32; kk++) {
            const float4 av = *(const float4*)&As[kk][ty * 4];
            const float4 bv = *(const float4*)&Bs[kk][tx * 4];
            float a[4] = {av.x, av.y, av.z, av.w};
            float b[4] = {bv.x, bv.y, bv.z, bv.w};
            #pragma unroll
            for (int i = 0; i < 4; i++)
                #pragma unroll
                for (int j = 0; j < 4; j++)
                    acc[i][j] = fmaf(a[i], b[j], acc[i][j]);
        }
        __syncthreads();
    }
    const float ws = wscale_p[0];
    #pragma unroll
    for (int i = 0; i < 4; i++) {
        int m = m0 + ty * 4 + i;
        float sc = ws * ascale[m] / 127.0f;
        #pragma unroll
        for (int j = 0; j < 4; j++) {
            int n = n0 + tx * 4 + j;
            size_t oi = (size_t)m * N + n;
            float v = acc[i][j] * sc;
            if (mode == 1) v += aux[oi];
            else if (mode == 2) v = v / (1.0f + expf(-v)) * aux[oi];
            out[oi] = v;
        }
    }
}

// ---------------- causal attention, one block (128 threads) per (b,h,query) ----------------
// Q/K/V in [T, D] layout == [B,S,H,HD]; head h at column offset h*HD.
__global__ __launch_bounds__(128) void attn(
        const float* __restrict__ Q, const float* __restrict__ K,
        const float* __restrict__ V, float* __restrict__ O) {
    __shared__ float sc[S_DIM];
    __shared__ float ql[HD_DIM];
    __shared__ float red[128];
    const int tid = threadIdx.x;
    const int sq = blockIdx.x;
    const int bh = blockIdx.y;
    const int b = bh / H_DIM, h = bh % H_DIM;
    const float scale = 0.08838834764831845f;  // 1/sqrt(128)
    const size_t rowbase = ((size_t)(b * S_DIM + sq)) * D_DIM + h * HD_DIM;
    ql[tid] = Q[rowbase + tid];
    __syncthreads();
    const int nk = sq + 1;
    for (int k = tid; k < nk; k += 128) {
        const float* kp = K + ((size_t)(b * S_DIM + k)) * D_DIM + h * HD_DIM;
        float s = 0.f;
        #pragma unroll
        for (int j = 0; j < HD_DIM; j += 4) {
            s = fmaf(ql[j], kp[j], s);
            s = fmaf(ql[j + 1], kp[j + 1], s);
            s = fmaf(ql[j + 2], kp[j + 2], s);
            s = fmaf(ql[j + 3], kp[j + 3], s);
        }
        sc[k] = s * scale;
    }
    __syncthreads();
    float m = -INFINITY;
    for (int k = tid; k < nk; k += 128) m = fmaxf(m, sc[k]);
    red[tid] = m; __syncthreads();
    for (int s = 64; s > 0; s >>= 1) {
        if (tid < s) red[tid] = fmaxf(red[tid], red[tid + s]);
        __syncthreads();
    }
    m = red[0]; __syncthreads();
    float sum = 0.f;
    for (int k = tid; k < nk; k += 128) { float e = expf(sc[k] - m); sc[k] = e; sum += e; }
    red[tid] = sum; __syncthreads();
    for (int s = 64; s > 0; s >>= 1) {
        if (tid < s) red[tid] += red[tid + s];
        __syncthreads();
    }
    float denom = red[0]; __syncthreads();
    // PV: thread d accumulates over keys; coalesced V reads across d
    float acc = 0.f;
    const float* vb = V + (size_t)b * S_DIM * D_DIM + h * HD_DIM + tid;
    int k = 0;
    for (; k + 4 <= nk; k += 4) {
        acc = fmaf(sc[k],     vb[(size_t)k * D_DIM],       acc);
        acc = fmaf(sc[k + 1], vb[(size_t)(k + 1) * D_DIM], acc);
        acc = fmaf(sc[k + 2], vb[(size_t)(k + 2) * D_DIM], acc);
        acc = fmaf(sc[k + 3], vb[(size_t)(k + 3) * D_DIM], acc);
    }
    for (; k < nk; k++) acc = fmaf(sc[k], vb[(size_t)k * D_DIM], acc);
    O[rowbase + tid] = acc / denom;
}

extern "C" void kernel_launch(void* const* d_in, const int* in_sizes, int n_in,
                              void* d_out, int out_size, void* d_ws, size_t ws_size,
                              hipStream_t stream) {
    const float* x  = (const float*)d_in[0];
    const float* wq = (const float*)d_in[1];
    const float* wk = (const float*)d_in[2];
    const float* wv = (const float*)d_in[3];
    const float* wo = (const float*)d_in[4];
    const float* wg = (const float*)d_in[5];
    const float* wu = (const float*)d_in[6];
    const float* wd = (const float*)d_in[7];
    const float* n1 = (const float*)d_in[8];
    const float* n2 = (const float*)d_in[9];
    float* out = (float*)d_out;

    // ---- workspace arena (~160 MB) ----
    uint8_t* base = (uint8_t*)d_ws;
    size_t o = 0;
    auto alloc = [&](size_t bytes) -> uint8_t* {
        o = (o + 255) & ~(size_t)255;
        uint8_t* p = base + o;
        o += bytes;
        return p;
    };
    const size_t DD = (size_t)D_DIM * D_DIM;     // 4M
    const size_t MD = (size_t)MLP_DIM * D_DIM;   // 16M
    const size_t TD = (size_t)T_DIM * D_DIM;     // 4M
    const size_t TM = (size_t)T_DIM * MLP_DIM;   // 16M

    int8_t* wqQ = (int8_t*)alloc(DD);
    int8_t* wkQ = (int8_t*)alloc(DD);
    int8_t* wvQ = (int8_t*)alloc(DD);
    int8_t* woQ = (int8_t*)alloc(DD);
    int8_t* wgQ = (int8_t*)alloc(MD);
    int8_t* wuQ = (int8_t*)alloc(MD);
    int8_t* wdQ = (int8_t*)alloc(MD);
    float*  wsc  = (float*)alloc(8 * sizeof(float));
    float*  part = (float*)alloc(1024 * sizeof(float));
    float*  asc  = (float*)alloc(T_DIM * sizeof(float));
    int8_t* actQ = (int8_t*)alloc(TM);
    float*  F    = (float*)alloc(5 * TD * sizeof(float));
    float* Qf  = F;
    float* Kf  = F + TD;
    float* Vf  = F + 2 * TD;
    float* AOf = F + 3 * TD;
    float* x2f = F + 4 * TD;
    float* yuf = F;   // aliases Qf..AOf (exactly 4*TD = T*MLP floats); those are dead by then

    // ---- weight quantization (deterministic scale) ----
    const float* wptr[7] = {wq, wk, wv, wo, wg, wu, wd};
    int8_t* wqt[7] = {wqQ, wkQ, wvQ, woQ, wgQ, wuQ, wdQ};
    const size_t wn[7] = {DD, DD, DD, DD, MD, MD, MD};
    for (int i = 0; i < 7; i++) {
        wabs_partial<<<1024, 256, 0, stream>>>(wptr[i], (int)wn[i], part);
        wabs_final<<<1, 256, 0, stream>>>(part, 1024, (float)wn[i], wsc + i);
        quant_w<<<4096, 256, 0, stream>>>(wptr[i], (int)wn[i], wsc + i, wqt[i]);
    }

    // ---- attention half ----
    rmsnorm_quant<<<T_DIM, 256, 0, stream>>>(x, n1, actQ, asc, D_DIM);
    dim3 g1(D_DIM / 64, T_DIM / 64);
    gemm_q8<<<g1, 256, 0, stream>>>(actQ, wqQ, Qf, asc, wsc + 0, nullptr, T_DIM, D_DIM, D_DIM, 0);
    gemm_q8<<<g1, 256, 0, stream>>>(actQ, wkQ, Kf, asc, wsc + 1, nullptr, T_DIM, D_DIM, D_DIM, 0);
    gemm_q8<<<g1, 256, 0, stream>>>(actQ, wvQ, Vf, asc, wsc + 2, nullptr, T_DIM, D_DIM, D_DIM, 0);
    dim3 ga(S_DIM, B_DIM * H_DIM);
    attn<<<ga, 128, 0, stream>>>(Qf, Kf, Vf, AOf);
    act_quant<<<T_DIM, 256, 0, stream>>>(AOf, actQ, asc, D_DIM);
    gemm_q8<<<g1, 256, 0, stream>>>(actQ, woQ, x2f, asc, wsc + 3, x, T_DIM, D_DIM, D_DIM, 1);

    // ---- MLP half ----
    rmsnorm_quant<<<T_DIM, 256, 0, stream>>>(x2f, n2, actQ, asc, D_DIM);
    dim3 g2(MLP_DIM / 64, T_DIM / 64);
    gemm_q8<<<g2, 256, 0, stream>>>(actQ, wuQ, yuf, asc, wsc + 5, nullptr, T_DIM, MLP_DIM, D_DIM, 0);
    gemm_q8<<<g2, 256, 0, stream>>>(actQ, wgQ, yuf, asc, wsc + 4, yuf, T_DIM, MLP_DIM, D_DIM, 2);
    act_quant<<<T_DIM, 256, 0, stream>>>(yuf, actQ, asc, MLP_DIM);
    dim3 g3(D_DIM / 64, T_DIM / 64);
    gemm_q8<<<g3, 256, 0, stream>>>(actQ, wdQ, out, asc, wsc + 6, x2f, T_DIM, D_DIM, MLP_DIM, 1);
}

// Round 2
// 4442.696 us; speedup vs baseline: 1.5199x; 1.5199x over previous
//
#include <hip/hip_runtime.h>
#include <cstdint>
#include <cmath>

#define D_DIM   2048
#define S_DIM   1024
#define B_DIM   2
#define H_DIM   16
#define HD_DIM  128
#define MLP_DIM 8192
#define T_DIM   (B_DIM * S_DIM)   // 2048 tokens

// ---------------- block reductions (256 threads) ----------------
__device__ inline float block_reduce_sum_256(float v, float* sm) {
    int tid = threadIdx.x;
    sm[tid] = v; __syncthreads();
    for (int s = 128; s > 0; s >>= 1) {
        if (tid < s) sm[tid] += sm[tid + s];
        __syncthreads();
    }
    float r = sm[0]; __syncthreads();
    return r;
}
__device__ inline float block_reduce_max_256(float v, float* sm) {
    int tid = threadIdx.x;
    sm[tid] = v; __syncthreads();
    for (int s = 128; s > 0; s >>= 1) {
        if (tid < s) sm[tid] = fmaxf(sm[tid], sm[tid + s]);
        __syncthreads();
    }
    float r = sm[0]; __syncthreads();
    return r;
}

// ---------------- weight scale: sum |w| (two-stage, deterministic) ----------------
__global__ void wabs_partial(const float* __restrict__ w, int n, float* __restrict__ part) {
    __shared__ float sm[256];
    float s = 0.f;
    for (int i = blockIdx.x * 256 + threadIdx.x; i < n; i += 256 * gridDim.x)
        s += fabsf(w[i]);
    float tot = block_reduce_sum_256(s, sm);
    if (threadIdx.x == 0) part[blockIdx.x] = tot;
}
__global__ void wabs_final(const float* __restrict__ part, int np, float count, float* __restrict__ out) {
    __shared__ float sm[256];
    float s = 0.f;
    for (int i = threadIdx.x; i < np; i += 256) s += part[i];
    float tot = block_reduce_sum_256(s, sm);
    if (threadIdx.x == 0) out[0] = tot / count + 1e-8f;
}

// ---------------- ternary weight quantization ----------------
__global__ void quant_w(const float* __restrict__ w, int n, const float* __restrict__ wsp,
                        int8_t* __restrict__ q) {
    float ws = wsp[0];
    for (int i = blockIdx.x * 256 + threadIdx.x; i < n; i += 256 * gridDim.x) {
        float v = rintf(w[i] / ws);            // jnp.round = half-to-even = rintf
        v = fminf(1.f, fmaxf(-1.f, v));
        q[i] = (int8_t)v;
    }
}

// ---------------- fused rmsnorm + activation quantization (one block per token) ----------------
__global__ void rmsnorm_quant(const float* __restrict__ x, const float* __restrict__ nw,
                              int8_t* __restrict__ q, float* __restrict__ ascale, int Kdim) {
    __shared__ float sm[256];
    int t = blockIdx.x;
    const float* row = x + (size_t)t * Kdim;
    float s = 0.f;
    for (int i = threadIdx.x; i < Kdim; i += 256) { float v = row[i]; s += v * v; }
    float tot = block_reduce_sum_256(s, sm);
    float rms = sqrtf(tot / (float)Kdim + 1e-6f);
    float m = 0.f;
    for (int i = threadIdx.x; i < Kdim; i += 256) {
        float h = row[i] / rms * nw[i];
        m = fmaxf(m, fabsf(h));
    }
    float amax = block_reduce_max_256(m, sm);
    float as = amax + 1e-8f;
    if (threadIdx.x == 0) ascale[t] = as;
    for (int i = threadIdx.x; i < Kdim; i += 256) {
        float h = row[i] / rms * nw[i];
        float v = rintf(fminf(127.f, fmaxf(-128.f, h / as * 127.f)));
        q[(size_t)t * Kdim + i] = (int8_t)v;
    }
}

// ---------------- activation quantization, no norm (one block per token) ----------------
__global__ void act_quant(const float* __restrict__ x, int8_t* __restrict__ q,
                          float* __restrict__ ascale, int Kdim) {
    __shared__ float sm[256];
    int t = blockIdx.x;
    const float* row = x + (size_t)t * Kdim;
    float m = 0.f;
    for (int i = threadIdx.x; i < Kdim; i += 256) m = fmaxf(m, fabsf(row[i]));
    float amax = block_reduce_max_256(m, sm);
    float as = amax + 1e-8f;
    if (threadIdx.x == 0) ascale[t] = as;
    for (int i = threadIdx.x; i < Kdim; i += 256) {
        float v = rintf(fminf(127.f, fmaxf(-128.f, row[i] / as * 127.f)));
        q[(size_t)t * Kdim + i] = (int8_t)v;
    }
}

// ---------------- int8-in / fp32-exact GEMM (unchanged from R0) ----------------
__global__ __launch_bounds__(256) void gemm_q8(
        const int8_t* __restrict__ Aq, const int8_t* __restrict__ Wq,
        float* __restrict__ out, const float* __restrict__ ascale,
        const float* __restrict__ wscale_p, const float* __restrict__ aux,
        int T, int N, int K, int mode) {
    __shared__ float As[32][68];
    __shared__ float Bs[32][68];
    const int tid = threadIdx.x;
    const int tx = tid & 15, ty = tid >> 4;
    const int m0 = blockIdx.y * 64, n0 = blockIdx.x * 64;
    const int Kw = K >> 2;
    const int* A4 = (const int*)Aq;
    const int* B4 = (const int*)Wq;
    float acc[4][4] = {};
    for (int k0 = 0; k0 < Kw; k0 += 8) {
        #pragma unroll
        for (int p = 0; p < 2; p++) {
            int idx = tid + p * 256;
            int r = idx >> 3, j = idx & 7;
            int va = A4[(size_t)(m0 + r) * Kw + k0 + j];
            int vb = B4[(size_t)(n0 + r) * Kw + k0 + j];
            As[j * 4 + 0][r] = (float)((va << 24) >> 24);
            As[j * 4 + 1][r] = (float)((va << 16) >> 24);
            As[j * 4 + 2][r] = (float)((va << 8) >> 24);
            As[j * 4 + 3][r] = (float)(va >> 24);
            Bs[j * 4 + 0][r] = (float)((vb << 24) >> 24);
            Bs[j * 4 + 1][r] = (float)((vb << 16) >> 24);
            Bs[j * 4 + 2][r] = (float)((vb << 8) >> 24);
            Bs[j * 4 + 3][r] = (float)(vb >> 24);
        }
        __syncthreads();
        #pragma unroll
        for (int kk = 0; kk < 32; kk++) {
            const float4 av = *(const float4*)&As[kk][ty * 4];
            const float4 bv = *(const float4*)&Bs[kk][tx * 4];
            float a[4] = {av.x, av.y, av.z, av.w};
            float b[4] = {bv.x, bv.y, bv.z, bv.w};
            #pragma unroll
            for (int i = 0; i < 4; i++)
                #pragma unroll
                for (int j = 0; j < 4; j++)
                    acc[i][j] = fmaf(a[i], b[j], acc[i][j]);
        }
        __syncthreads();
    }
    const float ws = wscale_p[0];
    #pragma unroll
    for (int i = 0; i < 4; i++) {
        int m = m0 + ty * 4 + i;
        float sc = ws * ascale[m] / 127.0f;
        #pragma unroll
        for (int j = 0; j < 4; j++) {
            int n = n0 + tx * 4 + j;
            size_t oi = (size_t)m * N + n;
            float v = acc[i][j] * sc;
            if (mode == 1) v += aux[oi];
            else if (mode == 2) v = v / (1.0f + expf(-v)) * aux[oi];
            out[oi] = v;
        }
    }
}

// ---------------- tiled flash-style causal attention ----------------
// Grid: (S/32, B*H), 256 threads. One block handles 32 queries of one (b,h).
// Thread mapping: qi = tid>>3 (0..31 across block; 0..7 within a wave),
// kg = tid&7. Score phase: thread computes scores for (qi, ki=kg+8c), c=0..3.
// O phase: thread owns q=qi, d = kg*4 + 32*j (j=0..3) as 4 float4 accumulators.
// Online-softmax state (m,l) kept in registers, replicated across the 8 lanes
// of a q-row (deterministic; reduced with __shfl_xor over lanes 1,2,4).
__global__ __launch_bounds__(256) void attn_tiled(
        const float* __restrict__ Q, const float* __restrict__ K,
        const float* __restrict__ V, float* __restrict__ O) {
    __shared__ float Qs[32][132];
    __shared__ float Ks[32][132];
    __shared__ float Vs[32][132];
    __shared__ float Ps[32][33];
    const int tid = threadIdx.x;
    const int qi = tid >> 3;        // 0..31
    const int kg = tid & 7;         // 0..7
    const int qt = blockIdx.x;      // q-tile
    const int bh = blockIdx.y;
    const int b = bh >> 4, h = bh & 15;
    const float scale = 0.08838834764831845f;  // 1/sqrt(128)
    const size_t bbase = (size_t)b * S_DIM * D_DIM + h * HD_DIM;

    // stage Q tile (coalesced float4)
    #pragma unroll
    for (int p = 0; p < 4; p++) {
        int idx = tid + p * 256;
        int r = idx >> 5, c4 = idx & 31;
        float4 v = *(const float4*)&Q[bbase + (size_t)(qt * 32 + r) * D_DIM + c4 * 4];
        *(float4*)&Qs[r][c4 * 4] = v;
    }

    float4 acc[4] = {};
    float mrun = -INFINITY, lrun = 0.f;

    for (int kt = 0; kt <= qt; kt++) {
        __syncthreads();   // protect Ks/Vs/Ps from previous iteration's readers
        // stage K,V tile
        #pragma unroll
        for (int p = 0; p < 4; p++) {
            int idx = tid + p * 256;
            int r = idx >> 5, c4 = idx & 31;
            size_t g = bbase + (size_t)(kt * 32 + r) * D_DIM + c4 * 4;
            *(float4*)&Ks[r][c4 * 4] = *(const float4*)&K[g];
            *(float4*)&Vs[r][c4 * 4] = *(const float4*)&V[g];
        }
        __syncthreads();

        // scores: s[c] = Q[qi] . K[kg+8c]
        float s0 = 0.f, s1 = 0.f, s2 = 0.f, s3 = 0.f;
        #pragma unroll
        for (int j4 = 0; j4 < 32; j4++) {
            float4 qv = *(const float4*)&Qs[qi][j4 * 4];
            float4 k0 = *(const float4*)&Ks[kg][j4 * 4];
            float4 k1 = *(const float4*)&Ks[kg + 8][j4 * 4];
            float4 k2 = *(const float4*)&Ks[kg + 16][j4 * 4];
            float4 k3 = *(const float4*)&Ks[kg + 24][j4 * 4];
            s0 = fmaf(qv.x, k0.x, s0); s0 = fmaf(qv.y, k0.y, s0);
            s0 = fmaf(qv.z, k0.z, s0); s0 = fmaf(qv.w, k0.w, s0);
            s1 = fmaf(qv.x, k1.x, s1); s1 = fmaf(qv.y, k1.y, s1);
            s1 = fmaf(qv.z, k1.z, s1); s1 = fmaf(qv.w, k1.w, s1);
            s2 = fmaf(qv.x, k2.x, s2); s2 = fmaf(qv.y, k2.y, s2);
            s2 = fmaf(qv.z, k2.z, s2); s2 = fmaf(qv.w, k2.w, s2);
            s3 = fmaf(qv.x, k3.x, s3); s3 = fmaf(qv.y, k3.y, s3);
            s3 = fmaf(qv.z, k3.z, s3); s3 = fmaf(qv.w, k3.w, s3);
        }
        s0 *= scale; s1 *= scale; s2 *= scale; s3 *= scale;
        if (kt == qt) {     // causal mask inside diagonal tile: ki <= qi
            if (kg      > qi) s0 = -INFINITY;
            if (kg + 8  > qi) s1 = -INFINITY;
            if (kg + 16 > qi) s2 = -INFINITY;
            if (kg + 24 > qi) s3 = -INFINITY;
        }
        // row max over 32 entries: 4 local + shfl across the 8 lanes of the row
        float tm = fmaxf(fmaxf(s0, s1), fmaxf(s2, s3));
        tm = fmaxf(tm, __shfl_xor(tm, 1));
        tm = fmaxf(tm, __shfl_xor(tm, 2));
        tm = fmaxf(tm, __shfl_xor(tm, 4));
        float mnew = fmaxf(mrun, tm);
        float alpha = expf(mrun - mnew);   // first tile: exp(-inf)=0
        float p0 = expf(s0 - mnew), p1 = expf(s1 - mnew);
        float p2 = expf(s2 - mnew), p3 = expf(s3 - mnew);
        float rs = p0 + p1 + p2 + p3;
        rs += __shfl_xor(rs, 1);
        rs += __shfl_xor(rs, 2);
        rs += __shfl_xor(rs, 4);
        lrun = lrun * alpha + rs;
        mrun = mnew;
        // rescale O accumulators
        #pragma unroll
        for (int j = 0; j < 4; j++) {
            acc[j].x *= alpha; acc[j].y *= alpha;
            acc[j].z *= alpha; acc[j].w *= alpha;
        }
        // publish P for the PV phase
        Ps[qi][kg]      = p0;
        Ps[qi][kg + 8]  = p1;
        Ps[qi][kg + 16] = p2;
        Ps[qi][kg + 24] = p3;
        __syncthreads();

        // PV: acc[j] (d = kg*4 + 32*j) += sum_k P[qi][k] * V[k][d]
        #pragma unroll 8
        for (int k = 0; k < 32; k++) {
            float pw = Ps[qi][k];
            #pragma unroll
            for (int j = 0; j < 4; j++) {
                float4 vv = *(const float4*)&Vs[k][kg * 4 + 32 * j];
                acc[j].x = fmaf(pw, vv.x, acc[j].x);
                acc[j].y = fmaf(pw, vv.y, acc[j].y);
                acc[j].z = fmaf(pw, vv.z, acc[j].z);
                acc[j].w = fmaf(pw, vv.w, acc[j].w);
            }
        }
    }

    // epilogue: O = acc / l
    float inv = 1.0f / lrun;
    size_t orow = bbase + (size_t)(qt * 32 + qi) * D_DIM;
    #pragma unroll
    for (int j = 0; j < 4; j++) {
        float4 v = acc[j];
        v.x *= inv; v.y *= inv; v.z *= inv; v.w *= inv;
        *(float4*)&O[orow + kg * 4 + 32 * j] = v;
    }
}

extern "C" void kernel_launch(void* const* d_in, const int* in_sizes, int n_in,
                              void* d_out, int out_size, void* d_ws, size_t ws_size,
                              hipStream_t stream) {
    const float* x  = (const float*)d_in[0];
    const float* wq = (const float*)d_in[1];
    const float* wk = (const float*)d_in[2];
    const float* wv = (const float*)d_in[3];
    const float* wo = (const float*)d_in[4];
    const float* wg = (const float*)d_in[5];
    const float* wu = (const float*)d_in[6];
    const float* wd = (const float*)d_in[7];
    const float* n1 = (const float*)d_in[8];
    const float* n2 = (const float*)d_in[9];
    float* out = (float*)d_out;

    // ---- workspace arena ----
    uint8_t* base = (uint8_t*)d_ws;
    size_t o = 0;
    auto alloc = [&](size_t bytes) -> uint8_t* {
        o = (o + 255) & ~(size_t)255;
        uint8_t* p = base + o;
        o += bytes;
        return p;
    };
    const size_t DD = (size_t)D_DIM * D_DIM;
    const size_t MD = (size_t)MLP_DIM * D_DIM;
    const size_t TD = (size_t)T_DIM * D_DIM;
    const size_t TM = (size_t)T_DIM * MLP_DIM;

    int8_t* wqQ = (int8_t*)alloc(DD);
    int8_t* wkQ = (int8_t*)alloc(DD);
    int8_t* wvQ = (int8_t*)alloc(DD);
    int8_t* woQ = (int8_t*)alloc(DD);
    int8_t* wgQ = (int8_t*)alloc(MD);
    int8_t* wuQ = (int8_t*)alloc(MD);
    int8_t* wdQ = (int8_t*)alloc(MD);
    float*  wsc  = (float*)alloc(8 * sizeof(float));
    float*  part = (float*)alloc(1024 * sizeof(float));
    float*  asc  = (float*)alloc(T_DIM * sizeof(float));
    int8_t* actQ = (int8_t*)alloc(TM);
    float*  F    = (float*)alloc(5 * TD * sizeof(float));
    float* Qf  = F;
    float* Kf  = F + TD;
    float* Vf  = F + 2 * TD;
    float* AOf = F + 3 * TD;
    float* x2f = F + 4 * TD;
    float* yuf = F;   // aliases Qf..AOf (4*TD = T*MLP floats); dead by then

    // ---- weight quantization ----
    const float* wptr[7] = {wq, wk, wv, wo, wg, wu, wd};
    int8_t* wqt[7] = {wqQ, wkQ, wvQ, woQ, wgQ, wuQ, wdQ};
    const size_t wn[7] = {DD, DD, DD, DD, MD, MD, MD};
    for (int i = 0; i < 7; i++) {
        wabs_partial<<<1024, 256, 0, stream>>>(wptr[i], (int)wn[i], part);
        wabs_final<<<1, 256, 0, stream>>>(part, 1024, (float)wn[i], wsc + i);
        quant_w<<<4096, 256, 0, stream>>>(wptr[i], (int)wn[i], wsc + i, wqt[i]);
    }

    // ---- attention half ----
    rmsnorm_quant<<<T_DIM, 256, 0, stream>>>(x, n1, actQ, asc, D_DIM);
    dim3 g1(D_DIM / 64, T_DIM / 64);
    gemm_q8<<<g1, 256, 0, stream>>>(actQ, wqQ, Qf, asc, wsc + 0, nullptr, T_DIM, D_DIM, D_DIM, 0);
    gemm_q8<<<g1, 256, 0, stream>>>(actQ, wkQ, Kf, asc, wsc + 1, nullptr, T_DIM, D_DIM, D_DIM, 0);
    gemm_q8<<<g1, 256, 0, stream>>>(actQ, wvQ, Vf, asc, wsc + 2, nullptr, T_DIM, D_DIM, D_DIM, 0);
    dim3 ga(S_DIM / 32, B_DIM * H_DIM);
    attn_tiled<<<ga, 256, 0, stream>>>(Qf, Kf, Vf, AOf);
    act_quant<<<T_DIM, 256, 0, stream>>>(AOf, actQ, asc, D_DIM);
    gemm_q8<<<g1, 256, 0, stream>>>(actQ, woQ, x2f, asc, wsc + 3, x, T_DIM, D_DIM, D_DIM, 1);

    // ---- MLP half ----
    rmsnorm_quant<<<T_DIM, 256, 0, stream>>>(x2f, n2, actQ, asc, D_DIM);
    dim3 g2(MLP_DIM / 64, T_DIM / 64);
    gemm_q8<<<g2, 256, 0, stream>>>(actQ, wuQ, yuf, asc, wsc + 5, nullptr, T_DIM, MLP_DIM, D_DIM, 0);
    gemm_q8<<<g2, 256, 0, stream>>>(actQ, wgQ, yuf, asc, wsc + 4, yuf, T_DIM, MLP_DIM, D_DIM, 2);
    act_quant<<<T_DIM, 256, 0, stream>>>(yuf, actQ, asc, MLP_DIM);
    dim3 g3(D_DIM / 64, T_DIM / 64);
    gemm_q8<<<g3, 256, 0, stream>>>(actQ, wdQ, out, asc, wsc + 6, x2f, T_DIM, D_DIM, MLP_DIM, 1);
}

// Round 3
// 1479.184 us; speedup vs baseline: 4.5651x; 3.0035x over previous
//
#include <hip/hip_runtime.h>
#include <cstdint>
#include <cmath>

#define D_DIM   2048
#define S_DIM   1024
#define B_DIM   2
#define H_DIM   16
#define HD_DIM  128
#define MLP_DIM 8192
#define T_DIM   (B_DIM * S_DIM)   // 2048 tokens

typedef int v4i  __attribute__((ext_vector_type(4)));
typedef int v16i __attribute__((ext_vector_type(16)));

__device__ inline void gll16(const void* g, void* l) {
    __builtin_amdgcn_global_load_lds(
        (__attribute__((address_space(1))) void*)g,
        (__attribute__((address_space(3))) void*)l, 16, 0, 0);
}

// ---------------- block reductions (256 threads) ----------------
__device__ inline float block_reduce_sum_256(float v, float* sm) {
    int tid = threadIdx.x;
    sm[tid] = v; __syncthreads();
    for (int s = 128; s > 0; s >>= 1) {
        if (tid < s) sm[tid] += sm[tid + s];
        __syncthreads();
    }
    float r = sm[0]; __syncthreads();
    return r;
}
__device__ inline float block_reduce_max_256(float v, float* sm) {
    int tid = threadIdx.x;
    sm[tid] = v; __syncthreads();
    for (int s = 128; s > 0; s >>= 1) {
        if (tid < s) sm[tid] = fmaxf(sm[tid], sm[tid + s]);
        __syncthreads();
    }
    float r = sm[0]; __syncthreads();
    return r;
}

// ---------------- weight scale: sum |w| (two-stage, deterministic, float4) ----------------
__global__ void wabs_partial(const float4* __restrict__ w, int n4, float* __restrict__ part) {
    __shared__ float sm[256];
    float s = 0.f;
    for (int i = blockIdx.x * 256 + threadIdx.x; i < n4; i += 256 * gridDim.x) {
        float4 v = w[i];
        s += fabsf(v.x) + fabsf(v.y) + fabsf(v.z) + fabsf(v.w);
    }
    float tot = block_reduce_sum_256(s, sm);
    if (threadIdx.x == 0) part[blockIdx.x] = tot;
}
__global__ void wabs_final(const float* __restrict__ part, int np, float count, float* __restrict__ out) {
    __shared__ float sm[256];
    float s = 0.f;
    for (int i = threadIdx.x; i < np; i += 256) s += part[i];
    float tot = block_reduce_sum_256(s, sm);
    if (threadIdx.x == 0) out[0] = tot / count + 1e-8f;
}

// ---------------- ternary weight quantization (float4 -> char4) ----------------
__global__ void quant_w(const float4* __restrict__ w, int n4, const float* __restrict__ wsp,
                        char4* __restrict__ q) {
    float ws = wsp[0];
    for (int i = blockIdx.x * 256 + threadIdx.x; i < n4; i += 256 * gridDim.x) {
        float4 v = w[i];
        char4 c;
        c.x = (int8_t)fminf(1.f, fmaxf(-1.f, rintf(v.x / ws)));
        c.y = (int8_t)fminf(1.f, fmaxf(-1.f, rintf(v.y / ws)));
        c.z = (int8_t)fminf(1.f, fmaxf(-1.f, rintf(v.z / ws)));
        c.w = (int8_t)fminf(1.f, fmaxf(-1.f, rintf(v.w / ws)));
        q[i] = c;
    }
}

// ---------------- fused rmsnorm + activation quantization (one block per token) ----------------
__global__ void rmsnorm_quant(const float* __restrict__ x, const float* __restrict__ nw,
                              int8_t* __restrict__ q, float* __restrict__ ascale, int Kdim) {
    __shared__ float sm[256];
    int t = blockIdx.x;
    const float* row = x + (size_t)t * Kdim;
    float s = 0.f;
    for (int i = threadIdx.x; i < Kdim; i += 256) { float v = row[i]; s += v * v; }
    float tot = block_reduce_sum_256(s, sm);
    float rms = sqrtf(tot / (float)Kdim + 1e-6f);
    float m = 0.f;
    for (int i = threadIdx.x; i < Kdim; i += 256) {
        float h = row[i] / rms * nw[i];
        m = fmaxf(m, fabsf(h));
    }
    float amax = block_reduce_max_256(m, sm);
    float as = amax + 1e-8f;
    if (threadIdx.x == 0) ascale[t] = as;
    for (int i = threadIdx.x; i < Kdim; i += 256) {
        float h = row[i] / rms * nw[i];
        float v = rintf(fminf(127.f, fmaxf(-128.f, h / as * 127.f)));
        q[(size_t)t * Kdim + i] = (int8_t)v;
    }
}

// ---------------- activation quantization, no norm (one block per token) ----------------
__global__ void act_quant(const float* __restrict__ x, int8_t* __restrict__ q,
                          float* __restrict__ ascale, int Kdim) {
    __shared__ float sm[256];
    int t = blockIdx.x;
    const float* row = x + (size_t)t * Kdim;
    float m = 0.f;
    for (int i = threadIdx.x; i < Kdim; i += 256) m = fmaxf(m, fabsf(row[i]));
    float amax = block_reduce_max_256(m, sm);
    float as = amax + 1e-8f;
    if (threadIdx.x == 0) ascale[t] = as;
    for (int i = threadIdx.x; i < Kdim; i += 256) {
        float v = rintf(fminf(127.f, fmaxf(-128.f, row[i] / as * 127.f)));
        q[(size_t)t * Kdim + i] = (int8_t)v;
    }
}

// ---------------- int8 MFMA GEMM ----------------
// out[t,n] = (sum_k A[t,k]*W[n,k]) * wscale_p[n>>ws_shift] * ascale[t] / 127 (+aux modes)
// 128x128 block tile, BK=64, 4 waves; wave (wm,wn) owns 64x64 = 2x2 of 32x32x32 i8 MFMA.
// LDS layout: k-slice-major granules (granule = kc*128 + row, 16B each) so fragment
// ds_read_b128 is lane-consecutive (conflict-free) AND global_load_lds dest is contiguous.
// mode 0: store   mode 1: += aux   mode 2: silu(v)*aux
__global__ __launch_bounds__(256, 2) void gemm_mfma(
        const int8_t* __restrict__ Aq, const int8_t* __restrict__ Wq,
        float* __restrict__ out, const float* __restrict__ ascale,
        const float* __restrict__ wscale_p, const float* __restrict__ aux,
        int N, int K, int mode, int ws_shift) {
    __shared__ int8_t As[8192];   // 512 granules: [kc 0..3][row 0..127] * 16B
    __shared__ int8_t Bs[8192];
    const int tid = threadIdx.x;
    const int w = tid >> 6;          // wave 0..3
    const int l = tid & 63;
    const int wm = w & 1, wn = w >> 1;
    const int lk = l >> 5, lr = l & 31;
    const int m0blk = blockIdx.y * 128;
    const int n0blk = blockIdx.x * 128;

    // staging: wave w loads k-slice kc=w (16B) of all 128 rows (2 insts of 64 rows)
    const int8_t* ag0 = Aq + (size_t)(m0blk + l) * K + w * 16;
    const int8_t* ag1 = Aq + (size_t)(m0blk + 64 + l) * K + w * 16;
    const int8_t* bg0 = Wq + (size_t)(n0blk + l) * K + w * 16;
    const int8_t* bg1 = Wq + (size_t)(n0blk + 64 + l) * K + w * 16;
    int8_t* al = As + w * 2048;   // granule w*128
    int8_t* bl = Bs + w * 2048;

    // fragment LDS byte offsets: ((ks*2+lk)*128 + wm*64 + mt*32 + lr)*16
    const int aoff = (lk * 128 + wm * 64 + lr) * 16;
    const int boff = (lk * 128 + wn * 64 + lr) * 16;

    v16i acc[2][2] = {};
    const int nkt = K >> 6;
    for (int kt = 0; kt < nkt; ++kt) {
        __syncthreads();
        const int kb = kt * 64;
        gll16(ag0 + kb, al);
        gll16(ag1 + kb, al + 1024);
        gll16(bg0 + kb, bl);
        gll16(bg1 + kb, bl + 1024);
        __syncthreads();
        #pragma unroll
        for (int ks = 0; ks < 2; ++ks) {
            v4i a0 = *(const v4i*)(As + aoff + ks * 4096);
            v4i a1 = *(const v4i*)(As + aoff + ks * 4096 + 512);
            v4i b0 = *(const v4i*)(Bs + boff + ks * 4096);
            v4i b1 = *(const v4i*)(Bs + boff + ks * 4096 + 512);
            acc[0][0] = __builtin_amdgcn_mfma_i32_32x32x32_i8(a0, b0, acc[0][0], 0, 0, 0);
            acc[0][1] = __builtin_amdgcn_mfma_i32_32x32x32_i8(a0, b1, acc[0][1], 0, 0, 0);
            acc[1][0] = __builtin_amdgcn_mfma_i32_32x32x32_i8(a1, b0, acc[1][0], 0, 0, 0);
            acc[1][1] = __builtin_amdgcn_mfma_i32_32x32x32_i8(a1, b1, acc[1][1], 0, 0, 0);
        }
    }

    // epilogue: C/D layout col=lane&31, row=(r&3)+8*(r>>2)+4*(lane>>5)
    #pragma unroll
    for (int mt = 0; mt < 2; ++mt) {
        const int mbase = m0blk + wm * 64 + mt * 32 + 4 * lk;
        #pragma unroll
        for (int nt = 0; nt < 2; ++nt) {
            const int n = n0blk + wn * 64 + nt * 32 + lr;
            const float ws = wscale_p[n >> ws_shift];
            v16i a = acc[mt][nt];
            #pragma unroll
            for (int r = 0; r < 16; ++r) {
                int m = mbase + (r & 3) + 8 * (r >> 2);
                float sc = ws * ascale[m] / 127.0f;
                float v = (float)a[r] * sc;
                size_t oi = (size_t)m * N + n;
                if (mode == 1) v += aux[oi];
                else if (mode == 2) v = v / (1.0f + expf(-v)) * aux[oi];
                out[oi] = v;
            }
        }
    }
}

// ---------------- tiled flash-style causal attention ----------------
// Grid: (S/32, B*H), 256 threads. Q/K/V have row stride ldq (fused QKV buffer);
// O written with row stride D_DIM.
__global__ __launch_bounds__(256) void attn_tiled(
        const float* __restrict__ Q, const float* __restrict__ K,
        const float* __restrict__ V, float* __restrict__ O, int ldq) {
    __shared__ float Qs[32][132];
    __shared__ float Ks[32][132];
    __shared__ float Vs[32][132];
    __shared__ float Ps[32][33];
    const int tid = threadIdx.x;
    const int qi = tid >> 3;        // 0..31
    const int kg = tid & 7;         // 0..7
    const int qt = blockIdx.x;      // q-tile
    const int bh = blockIdx.y;
    const int b = bh >> 4, h = bh & 15;
    const float scale = 0.08838834764831845f;  // 1/sqrt(128)

    // stage Q tile (coalesced float4)
    #pragma unroll
    for (int p = 0; p < 4; p++) {
        int idx = tid + p * 256;
        int r = idx >> 5, c4 = idx & 31;
        float4 v = *(const float4*)&Q[(size_t)(b * S_DIM + qt * 32 + r) * ldq + h * HD_DIM + c4 * 4];
        *(float4*)&Qs[r][c4 * 4] = v;
    }

    float4 acc[4] = {};
    float mrun = -INFINITY, lrun = 0.f;

    for (int kt = 0; kt <= qt; kt++) {
        __syncthreads();
        #pragma unroll
        for (int p = 0; p < 4; p++) {
            int idx = tid + p * 256;
            int r = idx >> 5, c4 = idx & 31;
            size_t g = (size_t)(b * S_DIM + kt * 32 + r) * ldq + h * HD_DIM + c4 * 4;
            *(float4*)&Ks[r][c4 * 4] = *(const float4*)&K[g];
            *(float4*)&Vs[r][c4 * 4] = *(const float4*)&V[g];
        }
        __syncthreads();

        float s0 = 0.f, s1 = 0.f, s2 = 0.f, s3 = 0.f;
        #pragma unroll
        for (int j4 = 0; j4 < 32; j4++) {
            float4 qv = *(const float4*)&Qs[qi][j4 * 4];
            float4 k0 = *(const float4*)&Ks[kg][j4 * 4];
            float4 k1 = *(const float4*)&Ks[kg + 8][j4 * 4];
            float4 k2 = *(const float4*)&Ks[kg + 16][j4 * 4];
            float4 k3 = *(const float4*)&Ks[kg + 24][j4 * 4];
            s0 = fmaf(qv.x, k0.x, s0); s0 = fmaf(qv.y, k0.y, s0);
            s0 = fmaf(qv.z, k0.z, s0); s0 = fmaf(qv.w, k0.w, s0);
            s1 = fmaf(qv.x, k1.x, s1); s1 = fmaf(qv.y, k1.y, s1);
            s1 = fmaf(qv.z, k1.z, s1); s1 = fmaf(qv.w, k1.w, s1);
            s2 = fmaf(qv.x, k2.x, s2); s2 = fmaf(qv.y, k2.y, s2);
            s2 = fmaf(qv.z, k2.z, s2); s2 = fmaf(qv.w, k2.w, s2);
            s3 = fmaf(qv.x, k3.x, s3); s3 = fmaf(qv.y, k3.y, s3);
            s3 = fmaf(qv.z, k3.z, s3); s3 = fmaf(qv.w, k3.w, s3);
        }
        s0 *= scale; s1 *= scale; s2 *= scale; s3 *= scale;
        if (kt == qt) {
            if (kg      > qi) s0 = -INFINITY;
            if (kg + 8  > qi) s1 = -INFINITY;
            if (kg + 16 > qi) s2 = -INFINITY;
            if (kg + 24 > qi) s3 = -INFINITY;
        }
        float tm = fmaxf(fmaxf(s0, s1), fmaxf(s2, s3));
        tm = fmaxf(tm, __shfl_xor(tm, 1));
        tm = fmaxf(tm, __shfl_xor(tm, 2));
        tm = fmaxf(tm, __shfl_xor(tm, 4));
        float mnew = fmaxf(mrun, tm);
        float alpha = expf(mrun - mnew);
        float p0 = expf(s0 - mnew), p1 = expf(s1 - mnew);
        float p2 = expf(s2 - mnew), p3 = expf(s3 - mnew);
        float rs = p0 + p1 + p2 + p3;
        rs += __shfl_xor(rs, 1);
        rs += __shfl_xor(rs, 2);
        rs += __shfl_xor(rs, 4);
        lrun = lrun * alpha + rs;
        mrun = mnew;
        #pragma unroll
        for (int j = 0; j < 4; j++) {
            acc[j].x *= alpha; acc[j].y *= alpha;
            acc[j].z *= alpha; acc[j].w *= alpha;
        }
        Ps[qi][kg]      = p0;
        Ps[qi][kg + 8]  = p1;
        Ps[qi][kg + 16] = p2;
        Ps[qi][kg + 24] = p3;
        __syncthreads();

        #pragma unroll 8
        for (int k = 0; k < 32; k++) {
            float pw = Ps[qi][k];
            #pragma unroll
            for (int j = 0; j < 4; j++) {
                float4 vv = *(const float4*)&Vs[k][kg * 4 + 32 * j];
                acc[j].x = fmaf(pw, vv.x, acc[j].x);
                acc[j].y = fmaf(pw, vv.y, acc[j].y);
                acc[j].z = fmaf(pw, vv.z, acc[j].z);
                acc[j].w = fmaf(pw, vv.w, acc[j].w);
            }
        }
    }

    float inv = 1.0f / lrun;
    size_t orow = (size_t)(b * S_DIM + qt * 32 + qi) * D_DIM + h * HD_DIM;
    #pragma unroll
    for (int j = 0; j < 4; j++) {
        float4 v = acc[j];
        v.x *= inv; v.y *= inv; v.z *= inv; v.w *= inv;
        *(float4*)&O[orow + kg * 4 + 32 * j] = v;
    }
}

extern "C" void kernel_launch(void* const* d_in, const int* in_sizes, int n_in,
                              void* d_out, int out_size, void* d_ws, size_t ws_size,
                              hipStream_t stream) {
    const float* x  = (const float*)d_in[0];
    const float* wq = (const float*)d_in[1];
    const float* wk = (const float*)d_in[2];
    const float* wv = (const float*)d_in[3];
    const float* wo = (const float*)d_in[4];
    const float* wg = (const float*)d_in[5];
    const float* wu = (const float*)d_in[6];
    const float* wd = (const float*)d_in[7];
    const float* n1 = (const float*)d_in[8];
    const float* n2 = (const float*)d_in[9];
    float* out = (float*)d_out;

    // ---- workspace arena ----
    uint8_t* base = (uint8_t*)d_ws;
    size_t o = 0;
    auto alloc = [&](size_t bytes) -> uint8_t* {
        o = (o + 255) & ~(size_t)255;
        uint8_t* p = base + o;
        o += bytes;
        return p;
    };
    const size_t DD = (size_t)D_DIM * D_DIM;
    const size_t MD = (size_t)MLP_DIM * D_DIM;
    const size_t TD = (size_t)T_DIM * D_DIM;
    const size_t TM = (size_t)T_DIM * MLP_DIM;

    int8_t* wqkvQ = (int8_t*)alloc(3 * DD);   // q,k,v contiguous for fused GEMM
    int8_t* woQ   = (int8_t*)alloc(DD);
    int8_t* wgQ   = (int8_t*)alloc(MD);
    int8_t* wuQ   = (int8_t*)alloc(MD);
    int8_t* wdQ   = (int8_t*)alloc(MD);
    float*  wsc   = (float*)alloc(8 * sizeof(float));
    float*  part  = (float*)alloc(1024 * sizeof(float));
    float*  asc   = (float*)alloc(T_DIM * sizeof(float));
    int8_t* actQ  = (int8_t*)alloc(TM);
    float*  F     = (float*)alloc(5 * TD * sizeof(float));
    float* QKVf = F;            // [T, 6144]
    float* AOf  = F + 3 * TD;
    float* x2f  = F + 4 * TD;
    float* yuf  = F;            // aliases QKV+AOf (4*TD = T*MLP floats); dead by then

    // ---- weight quantization (order: q,k,v,o,g,u,d -> wsc[0..6]) ----
    const float* wptr[7] = {wq, wk, wv, wo, wg, wu, wd};
    int8_t* wqt[7] = {wqkvQ, wqkvQ + DD, wqkvQ + 2 * DD, woQ, wgQ, wuQ, wdQ};
    const size_t wn[7] = {DD, DD, DD, DD, MD, MD, MD};
    for (int i = 0; i < 7; i++) {
        int n4 = (int)(wn[i] >> 2);
        wabs_partial<<<1024, 256, 0, stream>>>((const float4*)wptr[i], n4, part);
        wabs_final<<<1, 256, 0, stream>>>(part, 1024, (float)wn[i], wsc + i);
        quant_w<<<2048, 256, 0, stream>>>((const float4*)wptr[i], n4, wsc + i, (char4*)wqt[i]);
    }

    // ---- attention half ----
    rmsnorm_quant<<<T_DIM, 256, 0, stream>>>(x, n1, actQ, asc, D_DIM);
    dim3 gqkv(3 * D_DIM / 128, T_DIM / 128);
    gemm_mfma<<<gqkv, 256, 0, stream>>>(actQ, wqkvQ, QKVf, asc, wsc + 0, nullptr,
                                        3 * D_DIM, D_DIM, 0, 11);
    dim3 ga(S_DIM / 32, B_DIM * H_DIM);
    attn_tiled<<<ga, 256, 0, stream>>>(QKVf, QKVf + D_DIM, QKVf + 2 * D_DIM, AOf, 3 * D_DIM);
    act_quant<<<T_DIM, 256, 0, stream>>>(AOf, actQ, asc, D_DIM);
    dim3 g1(D_DIM / 128, T_DIM / 128);
    gemm_mfma<<<g1, 256, 0, stream>>>(actQ, woQ, x2f, asc, wsc + 3, x,
                                      D_DIM, D_DIM, 1, 30);

    // ---- MLP half ----
    rmsnorm_quant<<<T_DIM, 256, 0, stream>>>(x2f, n2, actQ, asc, D_DIM);
    dim3 g2(MLP_DIM / 128, T_DIM / 128);
    gemm_mfma<<<g2, 256, 0, stream>>>(actQ, wuQ, yuf, asc, wsc + 5, nullptr,
                                      MLP_DIM, D_DIM, 0, 30);
    gemm_mfma<<<g2, 256, 0, stream>>>(actQ, wgQ, yuf, asc, wsc + 4, yuf,
                                      MLP_DIM, D_DIM, 2, 30);
    act_quant<<<T_DIM, 256, 0, stream>>>(yuf, actQ, asc, MLP_DIM);
    dim3 g3(D_DIM / 128, T_DIM / 128);
    gemm_mfma<<<g3, 256, 0, stream>>>(actQ, wdQ, out, asc, wsc + 6, x2f,
                                      D_DIM, MLP_DIM, 1, 30);
}

// Round 4
// 1031.512 us; speedup vs baseline: 6.5463x; 1.4340x over previous
//
#include <hip/hip_runtime.h>
#include <cstdint>
#include <cmath>

#define D_DIM   2048
#define S_DIM   1024
#define B_DIM   2
#define H_DIM   16
#define HD_DIM  128
#define MLP_DIM 8192
#define T_DIM   (B_DIM * S_DIM)   // 2048 tokens
#define LDQ     (3 * D_DIM)       // fused QKV row stride

typedef int      v4i  __attribute__((ext_vector_type(4)));
typedef int      v16i __attribute__((ext_vector_type(16)));
typedef _Float16 v8h  __attribute__((ext_vector_type(8)));
typedef float    v16f __attribute__((ext_vector_type(16)));

__device__ inline void gll16(const void* g, void* l) {
    __builtin_amdgcn_global_load_lds(
        (__attribute__((address_space(1))) void*)g,
        (__attribute__((address_space(3))) void*)l, 16, 0, 0);
}

__device__ inline v16f zero16() {
    v16f z;
    #pragma unroll
    for (int i = 0; i < 16; ++i) z[i] = 0.f;
    return z;
}

// ---------------- block reductions (256 threads) ----------------
__device__ inline float block_reduce_sum_256(float v, float* sm) {
    int tid = threadIdx.x;
    sm[tid] = v; __syncthreads();
    for (int s = 128; s > 0; s >>= 1) {
        if (tid < s) sm[tid] += sm[tid + s];
        __syncthreads();
    }
    float r = sm[0]; __syncthreads();
    return r;
}
__device__ inline float block_reduce_max_256(float v, float* sm) {
    int tid = threadIdx.x;
    sm[tid] = v; __syncthreads();
    for (int s = 128; s > 0; s >>= 1) {
        if (tid < s) sm[tid] = fmaxf(sm[tid], sm[tid + s]);
        __syncthreads();
    }
    float r = sm[0]; __syncthreads();
    return r;
}

// ---------------- fused weight prep: 7 weights in 3 launches ----------------
struct WPack {
    const float4* w[7];
    char4*        q[7];
    int           n4[7];
};

__global__ void wabs_partial_all(WPack p, float* __restrict__ part) {
    __shared__ float sm[256];
    const int wi = blockIdx.y;
    const float4* w = p.w[wi];
    const int n4 = p.n4[wi];
    float s = 0.f;
    for (int i = blockIdx.x * 256 + threadIdx.x; i < n4; i += 256 * 1024) {
        float4 v = w[i];
        s += fabsf(v.x) + fabsf(v.y) + fabsf(v.z) + fabsf(v.w);
    }
    float tot = block_reduce_sum_256(s, sm);
    if (threadIdx.x == 0) part[wi * 1024 + blockIdx.x] = tot;
}
__global__ void wabs_final_all(const float* __restrict__ part, WPack p,
                               float* __restrict__ wsc) {
    __shared__ float sm[256];
    const int wi = blockIdx.x;
    float s = 0.f;
    for (int i = threadIdx.x; i < 1024; i += 256) s += part[wi * 1024 + i];
    float tot = block_reduce_sum_256(s, sm);
    if (threadIdx.x == 0) wsc[wi] = tot / (float)(p.n4[wi] * 4) + 1e-8f;
}
__global__ void quant_w_all(WPack p, const float* __restrict__ wsc) {
    const int wi = blockIdx.y;
    const float ws = wsc[wi];
    const float4* w = p.w[wi];
    char4* q = p.q[wi];
    const int n4 = p.n4[wi];
    for (int i = blockIdx.x * 256 + threadIdx.x; i < n4; i += 256 * 2048) {
        float4 v = w[i];
        char4 c;
        c.x = (int8_t)fminf(1.f, fmaxf(-1.f, rintf(v.x / ws)));
        c.y = (int8_t)fminf(1.f, fmaxf(-1.f, rintf(v.y / ws)));
        c.z = (int8_t)fminf(1.f, fmaxf(-1.f, rintf(v.z / ws)));
        c.w = (int8_t)fminf(1.f, fmaxf(-1.f, rintf(v.w / ws)));
        q[i] = c;
    }
}

// ---------------- fused rmsnorm + activation quantization ----------------
__global__ void rmsnorm_quant(const float* __restrict__ x, const float* __restrict__ nw,
                              int8_t* __restrict__ q, float* __restrict__ ascale, int Kdim) {
    __shared__ float sm[256];
    int t = blockIdx.x;
    const float* row = x + (size_t)t * Kdim;
    float s = 0.f;
    for (int i = threadIdx.x; i < Kdim; i += 256) { float v = row[i]; s += v * v; }
    float tot = block_reduce_sum_256(s, sm);
    float rms = sqrtf(tot / (float)Kdim + 1e-6f);
    float m = 0.f;
    for (int i = threadIdx.x; i < Kdim; i += 256) {
        float h = row[i] / rms * nw[i];
        m = fmaxf(m, fabsf(h));
    }
    float amax = block_reduce_max_256(m, sm);
    float as = amax + 1e-8f;
    if (threadIdx.x == 0) ascale[t] = as;
    for (int i = threadIdx.x; i < Kdim; i += 256) {
        float h = row[i] / rms * nw[i];
        float v = rintf(fminf(127.f, fmaxf(-128.f, h / as * 127.f)));
        q[(size_t)t * Kdim + i] = (int8_t)v;
    }
}

__global__ void act_quant(const float* __restrict__ x, int8_t* __restrict__ q,
                          float* __restrict__ ascale, int Kdim) {
    __shared__ float sm[256];
    int t = blockIdx.x;
    const float* row = x + (size_t)t * Kdim;
    float m = 0.f;
    for (int i = threadIdx.x; i < Kdim; i += 256) m = fmaxf(m, fabsf(row[i]));
    float amax = block_reduce_max_256(m, sm);
    float as = amax + 1e-8f;
    if (threadIdx.x == 0) ascale[t] = as;
    for (int i = threadIdx.x; i < Kdim; i += 256) {
        float v = rintf(fminf(127.f, fmaxf(-128.f, row[i] / as * 127.f)));
        q[(size_t)t * Kdim + i] = (int8_t)v;
    }
}

// ---------------- int8 MFMA GEMM (unchanged from R3, verified) ----------------
__global__ __launch_bounds__(256, 2) void gemm_mfma(
        const int8_t* __restrict__ Aq, const int8_t* __restrict__ Wq,
        float* __restrict__ out, const float* __restrict__ ascale,
        const float* __restrict__ wscale_p, const float* __restrict__ aux,
        int N, int K, int mode, int ws_shift) {
    __shared__ int8_t As[8192];   // 512 granules: [kc 0..3][row 0..127] * 16B
    __shared__ int8_t Bs[8192];
    const int tid = threadIdx.x;
    const int w = tid >> 6;
    const int l = tid & 63;
    const int wm = w & 1, wn = w >> 1;
    const int lk = l >> 5, lr = l & 31;
    const int m0blk = blockIdx.y * 128;
    const int n0blk = blockIdx.x * 128;

    const int8_t* ag0 = Aq + (size_t)(m0blk + l) * K + w * 16;
    const int8_t* ag1 = Aq + (size_t)(m0blk + 64 + l) * K + w * 16;
    const int8_t* bg0 = Wq + (size_t)(n0blk + l) * K + w * 16;
    const int8_t* bg1 = Wq + (size_t)(n0blk + 64 + l) * K + w * 16;
    int8_t* al = As + w * 2048;
    int8_t* bl = Bs + w * 2048;

    const int aoff = (lk * 128 + wm * 64 + lr) * 16;
    const int boff = (lk * 128 + wn * 64 + lr) * 16;

    v16i acc[2][2] = {};
    const int nkt = K >> 6;
    for (int kt = 0; kt < nkt; ++kt) {
        __syncthreads();
        const int kb = kt * 64;
        gll16(ag0 + kb, al);
        gll16(ag1 + kb, al + 1024);
        gll16(bg0 + kb, bl);
        gll16(bg1 + kb, bl + 1024);
        __syncthreads();
        #pragma unroll
        for (int ks = 0; ks < 2; ++ks) {
            v4i a0 = *(const v4i*)(As + aoff + ks * 4096);
            v4i a1 = *(const v4i*)(As + aoff + ks * 4096 + 512);
            v4i b0 = *(const v4i*)(Bs + boff + ks * 4096);
            v4i b1 = *(const v4i*)(Bs + boff + ks * 4096 + 512);
            acc[0][0] = __builtin_amdgcn_mfma_i32_32x32x32_i8(a0, b0, acc[0][0], 0, 0, 0);
            acc[0][1] = __builtin_amdgcn_mfma_i32_32x32x32_i8(a0, b1, acc[0][1], 0, 0, 0);
            acc[1][0] = __builtin_amdgcn_mfma_i32_32x32x32_i8(a1, b0, acc[1][0], 0, 0, 0);
            acc[1][1] = __builtin_amdgcn_mfma_i32_32x32x32_i8(a1, b1, acc[1][1], 0, 0, 0);
        }
    }

    #pragma unroll
    for (int mt = 0; mt < 2; ++mt) {
        const int mbase = m0blk + wm * 64 + mt * 32 + 4 * lk;
        #pragma unroll
        for (int nt = 0; nt < 2; ++nt) {
            const int n = n0blk + wn * 64 + nt * 32 + lr;
            const float ws = wscale_p[n >> ws_shift];
            v16i a = acc[mt][nt];
            #pragma unroll
            for (int r = 0; r < 16; ++r) {
                int m = mbase + (r & 3) + 8 * (r >> 2);
                float sc = ws * ascale[m] / 127.0f;
                float v = (float)a[r] * sc;
                size_t oi = (size_t)m * N + n;
                if (mode == 1) v += aux[oi];
                else if (mode == 2) v = v / (1.0f + expf(-v)) * aux[oi];
                out[oi] = v;
            }
        }
    }
}

// ---------------- fp16 MFMA flash attention ----------------
// Grid (S/32, B*H), 64 threads = 1 wave per (b,h,32-query tile).
// Scores bounded (|s| <= 0.0884*||q||*||k|| ~ 4) -> fixed m=0 online softmax:
// no max tracking, no rescale. Denominator l via MFMA against all-ones B
// (row-sum replicated to every lane's C column). P round-trips LDS
// (C-layout -> A-layout). K LDS row-major + granule-XOR swizzle; V transposed.
__global__ __launch_bounds__(64) void attn_mfma(const float* __restrict__ QKV,
                                                float* __restrict__ O) {
    __shared__ __align__(16) char KsB[8192];   // fp16 [32 key][128 d], swizzled 16B granules
    __shared__ __align__(16) char VtB[8192];   // fp16 [128 d][32 key] transposed, swizzled
    __shared__ __align__(16) char PsB[2048];   // fp16 [32 q][32 key], swizzled
    const int l    = threadIdx.x;
    const int half = l >> 5;
    const int lr   = l & 31;
    const int qt   = blockIdx.x;
    const int bh   = blockIdx.y;
    const int b = bh >> 4, h = bh & 15;
    const int tok0 = b * S_DIM;
    const float scale = 0.08838834764831845f;  // 1/sqrt(128)

    // Q fragments (A-operand) in registers: lane holds Q[q=lr][d=16s+8*half+j]
    v8h qa[8];
    {
        const float* qrow = QKV + (size_t)(tok0 + qt * 32 + lr) * LDQ + h * HD_DIM;
        #pragma unroll
        for (int s = 0; s < 8; ++s) {
            const float* src = qrow + s * 16 + half * 8;
            float4 f0 = *(const float4*)src;
            float4 f1 = *(const float4*)(src + 4);
            union { _Float16 hh[8]; v8h v; } c;
            c.hh[0] = (_Float16)f0.x; c.hh[1] = (_Float16)f0.y;
            c.hh[2] = (_Float16)f0.z; c.hh[3] = (_Float16)f0.w;
            c.hh[4] = (_Float16)f1.x; c.hh[5] = (_Float16)f1.y;
            c.hh[6] = (_Float16)f1.z; c.hh[7] = (_Float16)f1.w;
            qa[s] = c.v;
        }
    }
    v8h ones;
    #pragma unroll
    for (int j = 0; j < 8; ++j) ones[j] = (_Float16)1.0f;

    v16f oacc[4] = {zero16(), zero16(), zero16(), zero16()};
    v16f lacc = zero16();

    for (int kt = 0; kt <= qt; ++kt) {
        const int kt0 = tok0 + kt * 32;

        // ---- stage K tile: row-major fp16, slot = granule ^ (key&15) ----
        #pragma unroll
        for (int it = 0; it < 8; ++it) {
            int unit = it * 64 + l;
            int key = unit >> 4, g = unit & 15;
            const float* src = QKV + (size_t)(kt0 + key) * LDQ + D_DIM + h * HD_DIM + g * 8;
            float4 f0 = *(const float4*)src;
            float4 f1 = *(const float4*)(src + 4);
            union { _Float16 hh[8]; v8h v; } c;
            c.hh[0] = (_Float16)f0.x; c.hh[1] = (_Float16)f0.y;
            c.hh[2] = (_Float16)f0.z; c.hh[3] = (_Float16)f0.w;
            c.hh[4] = (_Float16)f1.x; c.hh[5] = (_Float16)f1.y;
            c.hh[6] = (_Float16)f1.z; c.hh[7] = (_Float16)f1.w;
            *(v8h*)(KsB + key * 256 + ((g ^ (key & 15)) * 16)) = c.v;
        }
        // ---- stage V tile transposed: Vt[d][key], slot = keygranule ^ (d&3) ----
        #pragma unroll
        for (int it = 0; it < 4; ++it) {
            int unit = it * 64 + l;
            int kp = unit & 15, g = unit >> 4;
            const float* s0 = QKV + (size_t)(kt0 + 2 * kp) * LDQ + 2 * D_DIM + h * HD_DIM + g * 8;
            const float* s1 = s0 + LDQ;
            float4 a0 = *(const float4*)s0, a1 = *(const float4*)(s0 + 4);
            float4 b0 = *(const float4*)s1, b1 = *(const float4*)(s1 + 4);
            float va[8] = {a0.x, a0.y, a0.z, a0.w, a1.x, a1.y, a1.z, a1.w};
            float vb[8] = {b0.x, b0.y, b0.z, b0.w, b1.x, b1.y, b1.z, b1.w};
            int kg = kp >> 2, ko = (kp & 3) * 4;
            #pragma unroll
            for (int j = 0; j < 8; ++j) {
                int d = g * 8 + j;
                union { _Float16 hh[2]; unsigned u; } pk;
                pk.hh[0] = (_Float16)va[j];
                pk.hh[1] = (_Float16)vb[j];
                *(unsigned*)(VtB + d * 64 + ((kg ^ (d & 3)) * 16) + ko) = pk.u;
            }
        }

        // ---- QK^T: S[q][key], contraction over d (8 MFMA steps) ----
        v16f sacc = zero16();
        #pragma unroll
        for (int s = 0; s < 8; ++s) {
            int gi = half + 2 * s;
            v8h kb = *(const v8h*)(KsB + lr * 256 + ((gi ^ (lr & 15)) * 16));
            sacc = __builtin_amdgcn_mfma_f32_32x32x16_f16(qa[s], kb, sacc, 0, 0, 0);
        }

        // ---- P = exp(scale*s) (m=0), causal mask on diagonal tile; P -> LDS ----
        const bool diag = (kt == qt);
        #pragma unroll
        for (int r = 0; r < 16; ++r) {
            int row = (r & 3) + 8 * (r >> 2) + 4 * half;   // q offset
            float p = (!diag || lr <= row) ? __expf(sacc[r] * scale) : 0.0f;
            int kg2 = lr >> 3;
            *(_Float16*)(PsB + row * 64 + ((kg2 ^ (row & 3)) * 16) + (lr & 7) * 2) = (_Float16)p;
        }

        // ---- PV + denominator: O[q][d] += P.V, l[q] += P.1 ----
        #pragma unroll
        for (int s2 = 0; s2 < 2; ++s2) {
            int pg = half + 2 * s2;
            v8h pa = *(const v8h*)(PsB + lr * 64 + ((pg ^ (lr & 3)) * 16));
            lacc = __builtin_amdgcn_mfma_f32_32x32x16_f16(pa, ones, lacc, 0, 0, 0);
            #pragma unroll
            for (int nt = 0; nt < 4; ++nt) {
                int d = nt * 32 + lr;
                int kgv = half + 2 * s2;
                v8h vbf = *(const v8h*)(VtB + d * 64 + ((kgv ^ (d & 3)) * 16));
                oacc[nt] = __builtin_amdgcn_mfma_f32_32x32x16_f16(pa, vbf, oacc[nt], 0, 0, 0);
            }
        }
    }

    // ---- epilogue: O = acc / l (l replicated across lanes by ones-MFMA) ----
    #pragma unroll
    for (int nt = 0; nt < 4; ++nt) {
        #pragma unroll
        for (int r = 0; r < 16; ++r) {
            int row = (r & 3) + 8 * (r >> 2) + 4 * half;
            float v = oacc[nt][r] / lacc[r];
            O[(size_t)(tok0 + qt * 32 + row) * D_DIM + h * HD_DIM + nt * 32 + lr] = v;
        }
    }
}

extern "C" void kernel_launch(void* const* d_in, const int* in_sizes, int n_in,
                              void* d_out, int out_size, void* d_ws, size_t ws_size,
                              hipStream_t stream) {
    const float* x  = (const float*)d_in[0];
    const float* n1 = (const float*)d_in[8];
    const float* n2 = (const float*)d_in[9];
    float* out = (float*)d_out;

    // ---- workspace arena ----
    uint8_t* base = (uint8_t*)d_ws;
    size_t o = 0;
    auto alloc = [&](size_t bytes) -> uint8_t* {
        o = (o + 255) & ~(size_t)255;
        uint8_t* p = base + o;
        o += bytes;
        return p;
    };
    const size_t DD = (size_t)D_DIM * D_DIM;
    const size_t MD = (size_t)MLP_DIM * D_DIM;
    const size_t TD = (size_t)T_DIM * D_DIM;
    const size_t TM = (size_t)T_DIM * MLP_DIM;

    int8_t* wqkvQ = (int8_t*)alloc(3 * DD);   // q,k,v contiguous for fused GEMM
    int8_t* woQ   = (int8_t*)alloc(DD);
    int8_t* wgQ   = (int8_t*)alloc(MD);
    int8_t* wuQ   = (int8_t*)alloc(MD);
    int8_t* wdQ   = (int8_t*)alloc(MD);
    float*  wsc   = (float*)alloc(8 * sizeof(float));
    float*  part  = (float*)alloc(7 * 1024 * sizeof(float));
    float*  asc   = (float*)alloc(T_DIM * sizeof(float));
    int8_t* actQ  = (int8_t*)alloc(TM);
    float*  F     = (float*)alloc(5 * TD * sizeof(float));
    float* QKVf = F;            // [T, 6144]
    float* AOf  = F + 3 * TD;
    float* x2f  = F + 4 * TD;
    float* yuf  = F;            // aliases QKV+AOf (4*TD = T*MLP floats); dead by then

    // ---- fused weight quantization: 3 launches for all 7 weights ----
    WPack p;
    p.w[0] = (const float4*)d_in[1];  p.q[0] = (char4*)wqkvQ;            p.n4[0] = (int)(DD >> 2);
    p.w[1] = (const float4*)d_in[2];  p.q[1] = (char4*)(wqkvQ + DD);     p.n4[1] = (int)(DD >> 2);
    p.w[2] = (const float4*)d_in[3];  p.q[2] = (char4*)(wqkvQ + 2 * DD); p.n4[2] = (int)(DD >> 2);
    p.w[3] = (const float4*)d_in[4];  p.q[3] = (char4*)woQ;              p.n4[3] = (int)(DD >> 2);
    p.w[4] = (const float4*)d_in[5];  p.q[4] = (char4*)wgQ;              p.n4[4] = (int)(MD >> 2);
    p.w[5] = (const float4*)d_in[6];  p.q[5] = (char4*)wuQ;              p.n4[5] = (int)(MD >> 2);
    p.w[6] = (const float4*)d_in[7];  p.q[6] = (char4*)wdQ;              p.n4[6] = (int)(MD >> 2);
    wabs_partial_all<<<dim3(1024, 7), 256, 0, stream>>>(p, part);
    wabs_final_all<<<7, 256, 0, stream>>>(part, p, wsc);
    quant_w_all<<<dim3(2048, 7), 256, 0, stream>>>(p, wsc);

    // ---- attention half ----
    rmsnorm_quant<<<T_DIM, 256, 0, stream>>>(x, n1, actQ, asc, D_DIM);
    dim3 gqkv(3 * D_DIM / 128, T_DIM / 128);
    gemm_mfma<<<gqkv, 256, 0, stream>>>(actQ, wqkvQ, QKVf, asc, wsc + 0, nullptr,
                                        3 * D_DIM, D_DIM, 0, 11);
    dim3 ga(S_DIM / 32, B_DIM * H_DIM);
    attn_mfma<<<ga, 64, 0, stream>>>(QKVf, AOf);
    act_quant<<<T_DIM, 256, 0, stream>>>(AOf, actQ, asc, D_DIM);
    dim3 g1(D_DIM / 128, T_DIM / 128);
    gemm_mfma<<<g1, 256, 0, stream>>>(actQ, woQ, x2f, asc, wsc + 3, x,
                                      D_DIM, D_DIM, 1, 30);

    // ---- MLP half ----
    rmsnorm_quant<<<T_DIM, 256, 0, stream>>>(x2f, n2, actQ, asc, D_DIM);
    dim3 g2(MLP_DIM / 128, T_DIM / 128);
    gemm_mfma<<<g2, 256, 0, stream>>>(actQ, wuQ, yuf, asc, wsc + 5, nullptr,
                                      MLP_DIM, D_DIM, 0, 30);
    gemm_mfma<<<g2, 256, 0, stream>>>(actQ, wgQ, yuf, asc, wsc + 4, yuf,
                                      MLP_DIM, D_DIM, 2, 30);
    act_quant<<<T_DIM, 256, 0, stream>>>(yuf, actQ, asc, MLP_DIM);
    dim3 g3(D_DIM / 128, T_DIM / 128);
    gemm_mfma<<<g3, 256, 0, stream>>>(actQ, wdQ, out, asc, wsc + 6, x2f,
                                      D_DIM, MLP_DIM, 1, 30);
}